// Round 11
// baseline (62.117 us; speedup 1.0000x reference)
//
#include <hip/hip_runtime.h>
#include <hip/hip_fp16.h>
#include <math.h>

#define NH 4        // heads
#define DD 64       // out features per head
#define NF 256      // NH*DD
#define KF 128      // in features
#define NN 4096     // nodes
#define NB 2        // batch
#define NG 8        // NB*NH groups
#define CH 32       // scan chunk length
#define NCH 128     // NN / CH
#define SUB 8       // elements per wave within a chunk (4 waves * 8 = CH)
#define TE 33       // table entries per chunk (0..32 inclusive prefixes)

typedef _Float16 h8_t __attribute__((ext_vector_type(8)));
typedef float f4_t __attribute__((ext_vector_type(4)));

// ---------------- Kernel 1: H = X @ W via fp16 MFMA (fp32 accum), fused s/d epilogue ----------------
__global__ __launch_bounds__(256) void k_gemm(const float* __restrict__ X,
                                              const float* __restrict__ W,
                                              const float* __restrict__ a_src,
                                              const float* __restrict__ a_dst,
                                              __half* __restrict__ Hout,
                                              float* __restrict__ s_arr,
                                              float* __restrict__ d_arr) {
  __shared__ float As[64][132];        // X tile, fp32
  __shared__ _Float16 WT[64][136];     // W block transposed [col][k] fp16
  const int bm = blockIdx.x;           // 0..127 row tile
  const int bn = blockIdx.y;           // 0..3 head
  const int tid = threadIdx.x;

  for (int i = tid; i < 64 * 32; i += 256) {
    int r = i >> 5, c4 = i & 31;
    float4 v = *(const float4*)(X + ((size_t)(bm * 64 + r)) * KF + c4 * 4);
    *(float4*)&As[r][c4 * 4] = v;
  }
  for (int i = tid; i < 64 * 128; i += 256) {
    int k = i >> 6, c = i & 63;
    WT[c][k] = (_Float16)W[(size_t)k * NF + bn * 64 + c];
  }
  __syncthreads();

  const int lane = tid & 63, w = tid >> 6;
  const int l15 = lane & 15, lq = lane >> 4;

  f4_t acc[4] = {f4_t{0.f,0.f,0.f,0.f}, f4_t{0.f,0.f,0.f,0.f},
                 f4_t{0.f,0.f,0.f,0.f}, f4_t{0.f,0.f,0.f,0.f}};

  #pragma unroll
  for (int kk = 0; kk < 4; ++kk) {
    const int koff = kk * 32 + lq * 8;
    h8_t a;
    {
      const float* ap = &As[w * 16 + l15][koff];
      float4 x0 = *(const float4*)ap;
      float4 x1 = *(const float4*)(ap + 4);
      a[0] = (_Float16)x0.x; a[1] = (_Float16)x0.y;
      a[2] = (_Float16)x0.z; a[3] = (_Float16)x0.w;
      a[4] = (_Float16)x1.x; a[5] = (_Float16)x1.y;
      a[6] = (_Float16)x1.z; a[7] = (_Float16)x1.w;
    }
    #pragma unroll
    for (int t = 0; t < 4; ++t) {
      h8_t b = *(const h8_t*)&WT[t * 16 + l15][koff];
      acc[t] = __builtin_amdgcn_mfma_f32_16x16x32_f16(a, b, acc[t], 0, 0, 0);
    }
  }

  float asv[4], adv[4];
  #pragma unroll
  for (int t = 0; t < 4; ++t) {
    asv[t] = a_src[bn * 64 + t * 16 + l15];
    adv[t] = a_dst[bn * 64 + t * 16 + l15];
  }
  #pragma unroll
  for (int j = 0; j < 4; ++j) {
    const int grow = bm * 64 + w * 16 + lq * 4 + j;
    float ps = 0.f, pd = 0.f;
    #pragma unroll
    for (int t = 0; t < 4; ++t) {
      float hv = acc[t][j];
      Hout[(size_t)grow * NF + bn * 64 + t * 16 + l15] = __float2half(hv);
      ps += hv * asv[t];
      pd += hv * adv[t];
    }
    #pragma unroll
    for (int off = 1; off < 16; off <<= 1) {
      ps += __shfl_xor(ps, off);
      pd += __shfl_xor(pd, off);
    }
    if (l15 == 0) {
      int b = grow >> 12, n = grow & (NN - 1);
      int g = b * NH + bn;
      s_arr[g * NN + n] = ps;
      d_arr[g * NN + n] = pd;
    }
  }
}

// ---------------- Kernel 2: packed-key bitonic sort, 8-element ownership ----------------
__global__ __launch_bounds__(512) void k_sort(const float* __restrict__ d_arr,
                                              const float* __restrict__ s_arr,
                                              float* __restrict__ dsort, int* __restrict__ dperm,
                                              float* __restrict__ tsort, int* __restrict__ tperm) {
  __shared__ unsigned skey[8][512];    // 16 KB, stride-4B per r: conflict-free
  __shared__ float vals[NN];           // 16 KB exact values for final gather
  const int bid = blockIdx.x;
  const bool isT = bid >= NG;
  const int g = isT ? bid - NG : bid;
  const float* src = isT ? s_arr : d_arr;
  float* okey = isT ? tsort : dsort;
  int* operm = isT ? tperm : dperm;
  const int tid = threadIdx.x;         // 0..511

  unsigned kk[8];
  {
    float4 v0 = *(const float4*)(src + g * NN + 8 * tid);
    float4 v1 = *(const float4*)(src + g * NN + 8 * tid + 4);
    float f[8] = {v0.x, v0.y, v0.z, v0.w, v1.x, v1.y, v1.z, v1.w};
    #pragma unroll
    for (int r = 0; r < 8; ++r) {
      float fv = isT ? -f[r] : f[r];
      vals[8 * tid + r] = fv;
      unsigned u = __float_as_uint(fv);
      u = (u & 0x80000000u) ? ~u : (u | 0x80000000u);   // order-preserving transform
      kk[r] = (u & 0xFFFFF000u) | (unsigned)(8 * tid + r);
    }
  }

  #define CEU(a, b, asc)                                           \
    do { unsigned ka = kk[a], kb = kk[b];                          \
      unsigned mn = ka < kb ? ka : kb, mx = ka < kb ? kb : ka;     \
      kk[a] = (asc) ? mn : mx; kk[b] = (asc) ? mx : mn; } while (0)

  CEU(0, 1, true); CEU(2, 3, false); CEU(4, 5, true); CEU(6, 7, false);
  CEU(0, 2, true); CEU(1, 3, true); CEU(4, 6, false); CEU(5, 7, false);
  CEU(0, 1, true); CEU(2, 3, true); CEU(4, 5, false); CEU(6, 7, false);

  #pragma unroll
  for (int k = 8; k <= NN; k <<= 1) {
    const bool asc = (tid & (k >> 3)) == 0;
    #pragma unroll
    for (int j = k >> 1; j > 0; j >>= 1) {
      if (j >= 512) {
        const int tdist = j >> 3;              // 64, 128, 256
        #pragma unroll
        for (int r = 0; r < 8; ++r) skey[r][tid] = kk[r];
        __syncthreads();
        const bool keepMin = ((tid & tdist) == 0) == asc;
        #pragma unroll
        for (int r = 0; r < 8; ++r) {
          unsigned pk = skey[r][tid ^ tdist];
          unsigned mn = kk[r] < pk ? kk[r] : pk;
          unsigned mx = kk[r] < pk ? pk : kk[r];
          kk[r] = keepMin ? mn : mx;
        }
        __syncthreads();
      } else if (j >= 8) {
        const int dist = j >> 3;               // 1..32, within-wave
        const bool keepMin = ((tid & dist) == 0) == asc;
        #pragma unroll
        for (int r = 0; r < 8; ++r) {
          unsigned pk = (unsigned)__shfl_xor((int)kk[r], dist);
          unsigned mn = kk[r] < pk ? kk[r] : pk;
          unsigned mx = kk[r] < pk ? pk : kk[r];
          kk[r] = keepMin ? mn : mx;
        }
      } else if (j == 4) {
        CEU(0, 4, asc); CEU(1, 5, asc); CEU(2, 6, asc); CEU(3, 7, asc);
      } else if (j == 2) {
        CEU(0, 2, asc); CEU(1, 3, asc); CEU(4, 6, asc); CEU(5, 7, asc);
      } else {
        CEU(0, 1, asc); CEU(2, 3, asc); CEU(4, 5, asc); CEU(6, 7, asc);
      }
    }
  }
  #undef CEU

  float ov[8]; int op[8];
  #pragma unroll
  for (int r = 0; r < 8; ++r) {
    int idx = (int)(kk[r] & 0xFFFu);
    ov[r] = vals[idx];
    op[r] = idx;
  }
  *(float4*)(okey + g * NN + 8 * tid)     = make_float4(ov[0], ov[1], ov[2], ov[3]);
  *(float4*)(okey + g * NN + 8 * tid + 4) = make_float4(ov[4], ov[5], ov[6], ov[7]);
  *(int4*)(operm + g * NN + 8 * tid)      = make_int4(op[0], op[1], op[2], op[3]);
  *(int4*)(operm + g * NN + 8 * tid + 4)  = make_int4(op[4], op[5], op[6], op[7]);
}

// ---------------- Kernel 3: per-chunk partial sums + FULL inclusive prefix tables ----------------
__global__ __launch_bounds__(256) void k_part(const __half* __restrict__ Hmat,
                                              const float* __restrict__ dsort,
                                              const int* __restrict__ dperm,
                                              float* __restrict__ chunkP, float* __restrict__ chunkS,
                                              float* __restrict__ chunkPw, float* __restrict__ chunkSw,
                                              float* __restrict__ PPtab, float* __restrict__ PStab,
                                              float* __restrict__ pwTab, float* __restrict__ swTab) {
  __shared__ float subP[4][64], subS[4][64];
  __shared__ float subPw[4], subSw[4];
  const int ch = blockIdx.x;   // 0..127
  const int g = blockIdx.y;    // 0..7
  const int b = g >> 2, h = g & 3;
  const int c = threadIdx.x & 63;
  const int w = threadIdx.x >> 6;
  const int gNN = g * NN;
  const size_t bNN = (size_t)b * NN;
  const int h64 = h * 64;
  const float dmax = dsort[gNN + NN - 1];
  const int kw0 = ch * CH + w * SUB;

  int j8[SUB]; float d8[SUB], hv8[SUB];
  #pragma unroll
  for (int l = 0; l < SUB; ++l) j8[l] = dperm[gNN + kw0 + l];
  #pragma unroll
  for (int l = 0; l < SUB; ++l) d8[l] = dsort[gNN + kw0 + l];
  #pragma unroll
  for (int l = 0; l < SUB; ++l) hv8[l] = __half2float(Hmat[(bNN + j8[l]) * NF + h64 + c]);

  float ppv[SUB], psv[SUB], ppw[SUB], psw[SUB];
  {
    float ap = 0.f, as = 0.f, aw = 0.f, aswv = 0.f;
    #pragma unroll
    for (int l = 0; l < SUB; ++l) {
      float wp = __expf(0.2f * (d8[l] - dmax));
      float w2 = wp * wp;
      float ws = w2 * w2 * wp;                // exp(d-dmax) = wp^5
      ap += wp * hv8[l]; as += ws * hv8[l]; aw += wp; aswv += ws;
      ppv[l] = ap; psv[l] = as; ppw[l] = aw; psw[l] = aswv;
    }
    subP[w][c] = ap; subS[w][c] = as;
    if (c == 0) { subPw[w] = aw; subSw[w] = aswv; }
  }
  __syncthreads();

  // cross-subchunk offsets (intra-block)
  float oP = 0.f, oS = 0.f, oPw = 0.f, oSw = 0.f;
  #pragma unroll
  for (int t = 0; t < 4; ++t) {
    if (t < w) { oP += subP[t][c]; oS += subS[t][c]; oPw += subPw[t]; oSw += subSw[t]; }
  }

  const size_t tb = (size_t)(g * NCH + ch) * TE;
  #pragma unroll
  for (int l = 0; l < SUB; ++l) {
    PPtab[(tb + w * SUB + 1 + l) * 64 + c] = ppv[l] + oP;
    PStab[(tb + w * SUB + 1 + l) * 64 + c] = psv[l] + oS;
  }
  if (c == 0) {
    #pragma unroll
    for (int l = 0; l < SUB; ++l) {
      pwTab[tb + w * SUB + 1 + l] = ppw[l] + oPw;
      swTab[tb + w * SUB + 1 + l] = psw[l] + oSw;
    }
  }
  if (w == 0) {
    PPtab[tb * 64 + c] = 0.f;
    PStab[tb * 64 + c] = 0.f;
    if (c == 0) { pwTab[tb] = 0.f; swTab[tb] = 0.f; }
    float tp = subP[0][c] + subP[1][c] + subP[2][c] + subP[3][c];
    float ts = subS[0][c] + subS[1][c] + subS[2][c] + subS[3][c];
    chunkP[(g * NCH + ch) * 64 + c] = tp;
    chunkS[(g * NCH + ch) * 64 + c] = ts;
    if (c == 0) {
      chunkPw[g * NCH + ch] = subPw[0] + subPw[1] + subPw[2] + subPw[3];
      chunkSw[g * NCH + ch] = subSw[0] + subSw[1] + subSw[2] + subSw[3];
    }
  }
}

// ---------------- Kernel 4: serve rows (loads prebuilt tables; no H gather, no exp rebuild) ----------------
__global__ __launch_bounds__(256, 4) void k_serve(const float* __restrict__ dsort,
                                                  const float* __restrict__ tsort,
                                                  const int* __restrict__ tperm,
                                                  const float* __restrict__ chunkP, const float* __restrict__ chunkS,
                                                  const float* __restrict__ chunkPw, const float* __restrict__ chunkSw,
                                                  const float* __restrict__ PPtab, const float* __restrict__ PStab,
                                                  const float* __restrict__ pwTab, const float* __restrict__ swTab,
                                                  const float* __restrict__ bias,
                                                  float* __restrict__ out) {
  __shared__ float PPloc[TE][64], PSloc[TE][64];    // 16.9 KB
  __shared__ float ppwLoc[TE], pswLoc[TE];
  __shared__ float subP[4][64], subS[4][64], sall[4][64];

  const int ch = blockIdx.x & (NCH - 1);
  const int g = blockIdx.x >> 7;
  const int b = g >> 2, h = g & 3;
  const int c = threadIdx.x & 63;
  const int w = threadIdx.x >> 6;
  const int tid = threadIdx.x;
  const int gNN = g * NN;
  const size_t bNN = (size_t)b * NN;
  const int h64 = h * 64;
  const float dmax = dsort[gNN + NN - 1];

  // --- load prebuilt tables into LDS (coalesced streaming) ---
  {
    const size_t tb = (size_t)(g * NCH + ch) * TE;
    const float4* srcP = (const float4*)(PPtab + tb * 64);
    const float4* srcS = (const float4*)(PStab + tb * 64);
    float4* dstP = (float4*)&PPloc[0][0];
    float4* dstS = (float4*)&PSloc[0][0];
    for (int i = tid; i < TE * 16; i += 256) { dstP[i] = srcP[i]; dstS[i] = srcS[i]; }
    if (tid < TE) {
      ppwLoc[tid] = pwTab[tb + tid];
      pswLoc[tid] = swTab[tb + tid];
    }
  }

  // --- cross-chunk channel offsets (prefix < ch) + total S, split over waves ---
  {
    float pp = 0.f, sp = 0.f, sa = 0.f;
    for (int t = w; t < ch; t += 4) pp += chunkP[(g * NCH + t) * 64 + c];
    for (int t = w; t < NCH; t += 4) {
      float v = chunkS[(g * NCH + t) * 64 + c];
      sa += v;
      if (t < ch) sp += v;
    }
    subP[w][c] = pp; subS[w][c] = sp; sall[w][c] = sa;
  }

  float offPw, offSw, totSw;
  {
    float w1 = chunkPw[g * NCH + c];
    float w2 = chunkPw[g * NCH + 64 + c];
    float pwo = (c < ch ? w1 : 0.f) + (c + 64 < ch ? w2 : 0.f);
    float u1 = chunkSw[g * NCH + c];
    float u2 = chunkSw[g * NCH + 64 + c];
    float swo = (c < ch ? u1 : 0.f) + (c + 64 < ch ? u2 : 0.f);
    float stw = u1 + u2;
    #pragma unroll
    for (int off = 1; off < 64; off <<= 1) {
      pwo += __shfl_xor(pwo, off);
      swo += __shfl_xor(swo, off);
      stw += __shfl_xor(stw, off);
    }
    offPw = pwo; offSw = swo; totSw = stw;
  }
  __syncthreads();

  const float offP = subP[0][c] + subP[1][c] + subP[2][c] + subP[3][c];
  const float offS = subS[0][c] + subS[1][c] + subS[2][c] + subS[3][c];
  const float totS = sall[0][c] + sall[1][c] + sall[2][c] + sall[3][c];

  // --- row range via 64-ary ballot searches ---
  const float* ts = tsort + gNN;
  int rlo, rhi;
  {
    const float p1 = ts[c * 64 + 63];
    if (ch == 0) rlo = 0;
    else {
      const float blo = dsort[gNN + ch * CH];
      unsigned long long m1 = __ballot(p1 < blo);
      int blk = __popcll(m1);
      if (blk == 64) rlo = NN;
      else {
        float p2 = ts[blk * 64 + c];
        unsigned long long m2 = __ballot(p2 < blo);
        rlo = blk * 64 + __popcll(m2);
      }
    }
    if (ch == NCH - 1) rhi = NN;
    else {
      const float bhi = dsort[gNN + (ch + 1) * CH];
      unsigned long long m1 = __ballot(p1 < bhi);
      int blk = __popcll(m1);
      if (blk == 64) rhi = NN;
      else {
        float p2 = ts[blk * 64 + c];
        unsigned long long m2 = __ballot(p2 < bhi);
        rhi = blk * 64 + __popcll(m2);
      }
    }
  }

  const float myd = (c < 32) ? dsort[gNN + ch * CH + c] : __int_as_float(0x7f800000);
  const float biasv = bias[h64 + c];

  // --- serve rows ---
  for (int r = rlo + w; r < rhi; r += 4) {
    const float t = ts[r];
    const int i = tperm[gNN + r];
    const int mloc = __popcll(__ballot(myd <= t));
    const float numB = PPloc[mloc][c] + offP;
    const float denB = ppwLoc[mloc] + offPw;
    const float numA = totS - (PSloc[mloc][c] + offS);
    const float denA = totSw - (pswLoc[mloc] + offSw);
    const float si = -t;
    const float sdm = si + dmax;
    const float mx = sdm > 0.f ? sdm : 0.2f * sdm;
    const float alpha = __expf(sdm - mx);
    const float beta = __expf(0.2f * sdm - mx);
    const float den = alpha * denA + beta * denB;
    float val = (alpha * numA + beta * numB) / den + biasv;
    float o = val > 0.f ? val : expm1f(val);
    out[(bNN + i) * NF + h64 + c] = o;
  }
}

extern "C" void kernel_launch(void* const* d_in, const int* in_sizes, int n_in,
                              void* d_out, int out_size, void* d_ws, size_t ws_size,
                              hipStream_t stream) {
  const float* X = (const float*)d_in[0];       // [2,4096,128]
  const float* W = (const float*)d_in[1];       // [128,256]
  const float* a_src = (const float*)d_in[2];   // [4,64,1]
  const float* a_dst = (const float*)d_in[3];   // [4,64,1]
  const float* bias = (const float*)d_in[4];    // [256]
  float* out = (float*)d_out;                   // [2,4096,256]

  float* ws = (float*)d_ws;
  float* s_arr = ws;                        // 8*4096
  float* d_arr = s_arr + NG * NN;           // 8*4096
  float* dsort = d_arr + NG * NN;           // 8*4096
  int* dperm = (int*)(dsort + NG * NN);     // 8*4096
  float* tsort = (float*)(dperm + NG * NN); // 8*4096
  int* tperm = (int*)(tsort + NG * NN);     // 8*4096
  float* chunkP = (float*)(tperm + NG * NN);    // 8*128*64
  float* chunkS = chunkP + NG * NCH * 64;
  float* chunkPw = chunkS + NG * NCH * 64;      // 8*128
  float* chunkSw = chunkPw + NG * NCH;
  float* PPtab = chunkSw + NG * NCH;            // 8*128*33*64 fp32 (8.65 MB)
  float* PStab = PPtab + (size_t)NG * NCH * TE * 64;
  float* pwTab = PStab + (size_t)NG * NCH * TE * 64;   // 8*128*33
  float* swTab = pwTab + (size_t)NG * NCH * TE;
  __half* Hmat = (__half*)(swTab + (size_t)NG * NCH * TE); // 2*4096*256 halves (4 MB)

  k_gemm<<<dim3(128, 4), 256, 0, stream>>>(X, W, a_src, a_dst, Hmat, s_arr, d_arr);
  k_sort<<<2 * NG, 512, 0, stream>>>(d_arr, s_arr, dsort, dperm, tsort, tperm);
  k_part<<<dim3(NCH, NG), 256, 0, stream>>>(Hmat, dsort, dperm, chunkP, chunkS, chunkPw, chunkSw,
                                            PPtab, PStab, pwTab, swTab);
  k_serve<<<NG * NCH, 256, 0, stream>>>(dsort, tsort, tperm,
                                        chunkP, chunkS, chunkPw, chunkSw,
                                        PPtab, PStab, pwTab, swTab, bias, out);
}

// Round 12
// 49.322 us; speedup vs baseline: 1.2594x; 1.2594x over previous
//
#include <hip/hip_runtime.h>
#include <hip/hip_fp16.h>
#include <math.h>

#define NH 4        // heads
#define DD 64       // out features per head
#define NF 256      // NH*DD
#define KF 128      // in features
#define NN 4096     // nodes
#define NB 2        // batch
#define NG 8        // NB*NH groups
#define CH 64       // scan chunk length (= wave width: full-wave rank ballot)
#define NCH 64      // NN / CH
#define PSUB 16     // elements per wave in k_part (4 waves * 16 = CH)
#define SSUB 8      // elements per wave in k_serve (8 waves * 8 = CH)
#define TE 65       // table entries per chunk (0..64 inclusive prefixes)

typedef _Float16 h8_t __attribute__((ext_vector_type(8)));
typedef float f4_t __attribute__((ext_vector_type(4)));

// ---------------- Kernel 1: H = X @ W via fp16 MFMA (fp32 accum), fused s/d epilogue ----------------
__global__ __launch_bounds__(256) void k_gemm(const float* __restrict__ X,
                                              const float* __restrict__ W,
                                              const float* __restrict__ a_src,
                                              const float* __restrict__ a_dst,
                                              __half* __restrict__ Hout,
                                              float* __restrict__ s_arr,
                                              float* __restrict__ d_arr) {
  __shared__ float As[64][132];        // X tile, fp32
  __shared__ _Float16 WT[64][136];     // W block transposed [col][k] fp16
  const int bm = blockIdx.x;           // 0..127 row tile
  const int bn = blockIdx.y;           // 0..3 head
  const int tid = threadIdx.x;

  for (int i = tid; i < 64 * 32; i += 256) {
    int r = i >> 5, c4 = i & 31;
    float4 v = *(const float4*)(X + ((size_t)(bm * 64 + r)) * KF + c4 * 4);
    *(float4*)&As[r][c4 * 4] = v;
  }
  for (int i = tid; i < 64 * 128; i += 256) {
    int k = i >> 6, c = i & 63;
    WT[c][k] = (_Float16)W[(size_t)k * NF + bn * 64 + c];
  }
  __syncthreads();

  const int lane = tid & 63, w = tid >> 6;
  const int l15 = lane & 15, lq = lane >> 4;

  f4_t acc[4] = {f4_t{0.f,0.f,0.f,0.f}, f4_t{0.f,0.f,0.f,0.f},
                 f4_t{0.f,0.f,0.f,0.f}, f4_t{0.f,0.f,0.f,0.f}};

  #pragma unroll
  for (int kk = 0; kk < 4; ++kk) {
    const int koff = kk * 32 + lq * 8;
    h8_t a;
    {
      const float* ap = &As[w * 16 + l15][koff];
      float4 x0 = *(const float4*)ap;
      float4 x1 = *(const float4*)(ap + 4);
      a[0] = (_Float16)x0.x; a[1] = (_Float16)x0.y;
      a[2] = (_Float16)x0.z; a[3] = (_Float16)x0.w;
      a[4] = (_Float16)x1.x; a[5] = (_Float16)x1.y;
      a[6] = (_Float16)x1.z; a[7] = (_Float16)x1.w;
    }
    #pragma unroll
    for (int t = 0; t < 4; ++t) {
      h8_t b = *(const h8_t*)&WT[t * 16 + l15][koff];
      acc[t] = __builtin_amdgcn_mfma_f32_16x16x32_f16(a, b, acc[t], 0, 0, 0);
    }
  }

  float asv[4], adv[4];
  #pragma unroll
  for (int t = 0; t < 4; ++t) {
    asv[t] = a_src[bn * 64 + t * 16 + l15];
    adv[t] = a_dst[bn * 64 + t * 16 + l15];
  }
  #pragma unroll
  for (int j = 0; j < 4; ++j) {
    const int grow = bm * 64 + w * 16 + lq * 4 + j;
    float ps = 0.f, pd = 0.f;
    #pragma unroll
    for (int t = 0; t < 4; ++t) {
      float hv = acc[t][j];
      Hout[(size_t)grow * NF + bn * 64 + t * 16 + l15] = __float2half(hv);
      ps += hv * asv[t];
      pd += hv * adv[t];
    }
    #pragma unroll
    for (int off = 1; off < 16; off <<= 1) {
      ps += __shfl_xor(ps, off);
      pd += __shfl_xor(pd, off);
    }
    if (l15 == 0) {
      int b = grow >> 12, n = grow & (NN - 1);
      int g = b * NH + bn;
      s_arr[g * NN + n] = ps;
      d_arr[g * NN + n] = pd;
    }
  }
}

// ---------------- Kernel 2: packed-key bitonic sort, 8-element ownership ----------------
__global__ __launch_bounds__(512) void k_sort(const float* __restrict__ d_arr,
                                              const float* __restrict__ s_arr,
                                              float* __restrict__ dsort, int* __restrict__ dperm,
                                              float* __restrict__ tsort, int* __restrict__ tperm) {
  __shared__ unsigned skey[8][512];    // 16 KB, stride-4B per r: conflict-free
  __shared__ float vals[NN];           // 16 KB exact values for final gather
  const int bid = blockIdx.x;
  const bool isT = bid >= NG;
  const int g = isT ? bid - NG : bid;
  const float* src = isT ? s_arr : d_arr;
  float* okey = isT ? tsort : dsort;
  int* operm = isT ? tperm : dperm;
  const int tid = threadIdx.x;         // 0..511

  unsigned kk[8];
  {
    float4 v0 = *(const float4*)(src + g * NN + 8 * tid);
    float4 v1 = *(const float4*)(src + g * NN + 8 * tid + 4);
    float f[8] = {v0.x, v0.y, v0.z, v0.w, v1.x, v1.y, v1.z, v1.w};
    #pragma unroll
    for (int r = 0; r < 8; ++r) {
      float fv = isT ? -f[r] : f[r];
      vals[8 * tid + r] = fv;
      unsigned u = __float_as_uint(fv);
      u = (u & 0x80000000u) ? ~u : (u | 0x80000000u);   // order-preserving transform
      kk[r] = (u & 0xFFFFF000u) | (unsigned)(8 * tid + r);
    }
  }

  #define CEU(a, b, asc)                                           \
    do { unsigned ka = kk[a], kb = kk[b];                          \
      unsigned mn = ka < kb ? ka : kb, mx = ka < kb ? kb : ka;     \
      kk[a] = (asc) ? mn : mx; kk[b] = (asc) ? mx : mn; } while (0)

  CEU(0, 1, true); CEU(2, 3, false); CEU(4, 5, true); CEU(6, 7, false);
  CEU(0, 2, true); CEU(1, 3, true); CEU(4, 6, false); CEU(5, 7, false);
  CEU(0, 1, true); CEU(2, 3, true); CEU(4, 5, false); CEU(6, 7, false);

  #pragma unroll
  for (int k = 8; k <= NN; k <<= 1) {
    const bool asc = (tid & (k >> 3)) == 0;
    #pragma unroll
    for (int j = k >> 1; j > 0; j >>= 1) {
      if (j >= 512) {
        const int tdist = j >> 3;              // 64, 128, 256
        #pragma unroll
        for (int r = 0; r < 8; ++r) skey[r][tid] = kk[r];
        __syncthreads();
        const bool keepMin = ((tid & tdist) == 0) == asc;
        #pragma unroll
        for (int r = 0; r < 8; ++r) {
          unsigned pk = skey[r][tid ^ tdist];
          unsigned mn = kk[r] < pk ? kk[r] : pk;
          unsigned mx = kk[r] < pk ? pk : kk[r];
          kk[r] = keepMin ? mn : mx;
        }
        __syncthreads();
      } else if (j >= 8) {
        const int dist = j >> 3;               // 1..32, within-wave
        const bool keepMin = ((tid & dist) == 0) == asc;
        #pragma unroll
        for (int r = 0; r < 8; ++r) {
          unsigned pk = (unsigned)__shfl_xor((int)kk[r], dist);
          unsigned mn = kk[r] < pk ? kk[r] : pk;
          unsigned mx = kk[r] < pk ? pk : kk[r];
          kk[r] = keepMin ? mn : mx;
        }
      } else if (j == 4) {
        CEU(0, 4, asc); CEU(1, 5, asc); CEU(2, 6, asc); CEU(3, 7, asc);
      } else if (j == 2) {
        CEU(0, 2, asc); CEU(1, 3, asc); CEU(4, 6, asc); CEU(5, 7, asc);
      } else {
        CEU(0, 1, asc); CEU(2, 3, asc); CEU(4, 5, asc); CEU(6, 7, asc);
      }
    }
  }
  #undef CEU

  float ov[8]; int op[8];
  #pragma unroll
  for (int r = 0; r < 8; ++r) {
    int idx = (int)(kk[r] & 0xFFFu);
    ov[r] = vals[idx];
    op[r] = idx;
  }
  *(float4*)(okey + g * NN + 8 * tid)     = make_float4(ov[0], ov[1], ov[2], ov[3]);
  *(float4*)(okey + g * NN + 8 * tid + 4) = make_float4(ov[4], ov[5], ov[6], ov[7]);
  *(int4*)(operm + g * NN + 8 * tid)      = make_int4(op[0], op[1], op[2], op[3]);
  *(int4*)(operm + g * NN + 8 * tid + 4)  = make_int4(op[4], op[5], op[6], op[7]);
}

// ---------------- Kernel 3: per-chunk partial sums (CH=64, 16-deep gather MLP per wave) ----------------
__global__ __launch_bounds__(256) void k_part(const __half* __restrict__ Hmat,
                                              const float* __restrict__ dsort,
                                              const int* __restrict__ dperm,
                                              float* __restrict__ chunkP, float* __restrict__ chunkS,
                                              float* __restrict__ chunkPw, float* __restrict__ chunkSw) {
  __shared__ float subP[4][64], subS[4][64];
  __shared__ float subPw[4], subSw[4];
  const int ch = blockIdx.x;   // 0..63
  const int g = blockIdx.y;    // 0..7
  const int b = g >> 2, h = g & 3;
  const int c = threadIdx.x & 63;
  const int w = threadIdx.x >> 6;
  const int gNN = g * NN;
  const size_t bNN = (size_t)b * NN;
  const int h64 = h * 64;
  const float dmax = dsort[gNN + NN - 1];
  const int kw0 = ch * CH + w * PSUB;

  int j16[PSUB]; float d16[PSUB], hv16[PSUB];
  #pragma unroll
  for (int l = 0; l < PSUB; ++l) j16[l] = dperm[gNN + kw0 + l];
  #pragma unroll
  for (int l = 0; l < PSUB; ++l) d16[l] = dsort[gNN + kw0 + l];
  #pragma unroll
  for (int l = 0; l < PSUB; ++l) hv16[l] = __half2float(Hmat[(bNN + j16[l]) * NF + h64 + c]);

  float pa = 0.f, sa = 0.f, pw = 0.f, sw = 0.f;
  #pragma unroll
  for (int l = 0; l < PSUB; ++l) {
    float wp = __expf(0.2f * (d16[l] - dmax));
    float w2 = wp * wp;
    float ws = w2 * w2 * wp;                  // exp(d-dmax) = wp^5
    pa += wp * hv16[l]; sa += ws * hv16[l]; pw += wp; sw += ws;
  }
  subP[w][c] = pa; subS[w][c] = sa;
  if (c == 0) { subPw[w] = pw; subSw[w] = sw; }
  __syncthreads();

  if (w == 0) {
    float tp = subP[0][c] + subP[1][c] + subP[2][c] + subP[3][c];
    float ts = subS[0][c] + subS[1][c] + subS[2][c] + subS[3][c];
    chunkP[(g * NCH + ch) * 64 + c] = tp;
    chunkS[(g * NCH + ch) * 64 + c] = ts;
    if (c == 0) {
      chunkPw[g * NCH + ch] = subPw[0] + subPw[1] + subPw[2] + subPw[3];
      chunkSw[g * NCH + ch] = subSw[0] + subSw[1] + subSw[2] + subSw[3];
    }
  }
}

// ---------------- Kernel 4: serve rows from local chunk prefixes (CH=64, 8 waves) ----------------
__global__ __launch_bounds__(512) void k_serve(const __half* __restrict__ Hmat,
                                               const float* __restrict__ dsort,
                                               const int* __restrict__ dperm,
                                               const float* __restrict__ tsort,
                                               const int* __restrict__ tperm,
                                               const float* __restrict__ chunkP, const float* __restrict__ chunkS,
                                               const float* __restrict__ chunkPw, const float* __restrict__ chunkSw,
                                               const float* __restrict__ bias,
                                               float* __restrict__ out) {
  __shared__ float PPloc[TE][64], PSloc[TE][64];    // 33.3 KB
  __shared__ float ppwLoc[TE], pswLoc[TE];
  __shared__ float subP[8][64], subS[8][64], sall[8][64];
  __shared__ float subPw[8], subSw[8];

  const int ch = blockIdx.x & (NCH - 1);
  const int g = blockIdx.x >> 6;
  const int b = g >> 2, h = g & 3;
  const int c = threadIdx.x & 63;
  const int w = threadIdx.x >> 6;           // 0..7
  const int gNN = g * NN;
  const size_t bNN = (size_t)b * NN;
  const int h64 = h * 64;
  const float dmax = dsort[gNN + NN - 1];
  const int kw0 = ch * CH + w * SSUB;

  // --- phase 1: gather own 8 elements, intra-sub inclusive prefixes ---
  int j8[SSUB]; float d8[SSUB], hv8[SSUB];
  #pragma unroll
  for (int l = 0; l < SSUB; ++l) j8[l] = dperm[gNN + kw0 + l];
  #pragma unroll
  for (int l = 0; l < SSUB; ++l) d8[l] = dsort[gNN + kw0 + l];
  #pragma unroll
  for (int l = 0; l < SSUB; ++l) hv8[l] = __half2float(Hmat[(bNN + j8[l]) * NF + h64 + c]);

  float ppv[SSUB], psv[SSUB], ppw[SSUB], psw[SSUB];
  {
    float ap = 0.f, as = 0.f, aw = 0.f, aswv = 0.f;
    #pragma unroll
    for (int l = 0; l < SSUB; ++l) {
      float wp = __expf(0.2f * (d8[l] - dmax));
      float w2 = wp * wp;
      float ws = w2 * w2 * wp;                // exp(d-dmax) = wp^5
      ap += wp * hv8[l]; as += ws * hv8[l]; aw += wp; aswv += ws;
      ppv[l] = ap; psv[l] = as; ppw[l] = aw; psw[l] = aswv;
    }
    subP[w][c] = ap; subS[w][c] = as;
    if (c == 0) { subPw[w] = aw; subSw[w] = aswv; }
  }
  __syncthreads();

  // --- phase 2: add earlier-subchunk offsets, publish local prefix tables ---
  {
    float oP = 0.f, oS = 0.f, oPw = 0.f, oSw = 0.f;
    #pragma unroll
    for (int t = 0; t < 8; ++t) {
      if (t < w) { oP += subP[t][c]; oS += subS[t][c]; oPw += subPw[t]; oSw += subSw[t]; }
    }
    #pragma unroll
    for (int l = 0; l < SSUB; ++l) {
      PPloc[w * SSUB + 1 + l][c] = ppv[l] + oP;
      PSloc[w * SSUB + 1 + l][c] = psv[l] + oS;
    }
    if (c == 0) {
      #pragma unroll
      for (int l = 0; l < SSUB; ++l) {
        ppwLoc[w * SSUB + 1 + l] = ppw[l] + oPw;
        pswLoc[w * SSUB + 1 + l] = psw[l] + oSw;
      }
    }
    if (w == 0) {
      PPloc[0][c] = 0.f; PSloc[0][c] = 0.f;
      if (c == 0) { ppwLoc[0] = 0.f; pswLoc[0] = 0.f; }
    }
  }
  __syncthreads();

  // --- phase 3: cross-chunk channel offsets (prefix < ch) + total S, split over 8 waves ---
  {
    float pp = 0.f, sp = 0.f, sa = 0.f;
    for (int t = w; t < ch; t += 8) pp += chunkP[(g * NCH + t) * 64 + c];
    for (int t = w; t < NCH; t += 8) {
      float v = chunkS[(g * NCH + t) * 64 + c];
      sa += v;
      if (t < ch) sp += v;
    }
    subP[w][c] = pp; subS[w][c] = sp; sall[w][c] = sa;
  }

  // scalar chunk offsets: NCH=64 -> one lane-read covers all chunks
  float offPw, offSw, totSw;
  {
    float w1 = chunkPw[g * NCH + c];
    float u1 = chunkSw[g * NCH + c];
    float pwo = (c < ch ? w1 : 0.f);
    float swo = (c < ch ? u1 : 0.f);
    float stw = u1;
    #pragma unroll
    for (int off = 1; off < 64; off <<= 1) {
      pwo += __shfl_xor(pwo, off);
      swo += __shfl_xor(swo, off);
      stw += __shfl_xor(stw, off);
    }
    offPw = pwo; offSw = swo; totSw = stw;
  }
  __syncthreads();

  float offP = 0.f, offS = 0.f, totS = 0.f;
  #pragma unroll
  for (int t = 0; t < 8; ++t) { offP += subP[t][c]; offS += subS[t][c]; totS += sall[t][c]; }

  // --- phase 4: row range via 64-ary ballot searches ---
  const float* ts = tsort + gNN;
  int rlo, rhi;
  {
    const float p1 = ts[c * 64 + 63];
    if (ch == 0) rlo = 0;
    else {
      const float blo = dsort[gNN + ch * CH];
      unsigned long long m1 = __ballot(p1 < blo);
      int blk = __popcll(m1);
      if (blk == 64) rlo = NN;
      else {
        float p2 = ts[blk * 64 + c];
        unsigned long long m2 = __ballot(p2 < blo);
        rlo = blk * 64 + __popcll(m2);
      }
    }
    if (ch == NCH - 1) rhi = NN;
    else {
      const float bhi = dsort[gNN + (ch + 1) * CH];
      unsigned long long m1 = __ballot(p1 < bhi);
      int blk = __popcll(m1);
      if (blk == 64) rhi = NN;
      else {
        float p2 = ts[blk * 64 + c];
        unsigned long long m2 = __ballot(p2 < bhi);
        rhi = blk * 64 + __popcll(m2);
      }
    }
  }

  const float myd = dsort[gNN + ch * CH + c];   // full-wave chunk keys (CH = 64)
  const float biasv = bias[h64 + c];

  // --- phase 5: serve rows (8 waves round-robin) ---
  for (int r = rlo + w; r < rhi; r += 8) {
    const float t = ts[r];
    const int i = tperm[gNN + r];
    const int mloc = __popcll(__ballot(myd <= t));     // 0..64
    const float numB = PPloc[mloc][c] + offP;
    const float denB = ppwLoc[mloc] + offPw;
    const float numA = totS - (PSloc[mloc][c] + offS);
    const float denA = totSw - (pswLoc[mloc] + offSw);
    const float si = -t;
    const float sdm = si + dmax;
    const float mx = sdm > 0.f ? sdm : 0.2f * sdm;
    const float alpha = __expf(sdm - mx);
    const float beta = __expf(0.2f * sdm - mx);
    const float den = alpha * denA + beta * denB;
    float val = (alpha * numA + beta * numB) / den + biasv;
    float o = val > 0.f ? val : expm1f(val);
    out[(bNN + i) * NF + h64 + c] = o;
  }
}

extern "C" void kernel_launch(void* const* d_in, const int* in_sizes, int n_in,
                              void* d_out, int out_size, void* d_ws, size_t ws_size,
                              hipStream_t stream) {
  const float* X = (const float*)d_in[0];       // [2,4096,128]
  const float* W = (const float*)d_in[1];       // [128,256]
  const float* a_src = (const float*)d_in[2];   // [4,64,1]
  const float* a_dst = (const float*)d_in[3];   // [4,64,1]
  const float* bias = (const float*)d_in[4];    // [256]
  float* out = (float*)d_out;                   // [2,4096,256]

  float* ws = (float*)d_ws;
  float* s_arr = ws;                        // 8*4096
  float* d_arr = s_arr + NG * NN;           // 8*4096
  float* dsort = d_arr + NG * NN;           // 8*4096
  int* dperm = (int*)(dsort + NG * NN);     // 8*4096
  float* tsort = (float*)(dperm + NG * NN); // 8*4096
  int* tperm = (int*)(tsort + NG * NN);     // 8*4096
  float* chunkP = (float*)(tperm + NG * NN);    // 8*64*64
  float* chunkS = chunkP + NG * NCH * 64;
  float* chunkPw = chunkS + NG * NCH * 64;      // 8*64
  float* chunkSw = chunkPw + NG * NCH;
  __half* Hmat = (__half*)(chunkSw + NG * NCH); // 2*4096*256 halves (4 MB)

  k_gemm<<<dim3(128, 4), 256, 0, stream>>>(X, W, a_src, a_dst, Hmat, s_arr, d_arr);
  k_sort<<<2 * NG, 512, 0, stream>>>(d_arr, s_arr, dsort, dperm, tsort, tperm);
  k_part<<<dim3(NCH, NG), 256, 0, stream>>>(Hmat, dsort, dperm, chunkP, chunkS, chunkPw, chunkSw);
  k_serve<<<NG * NCH, 512, 0, stream>>>(Hmat, dsort, dperm, tsort, tperm,
                                        chunkP, chunkS, chunkPw, chunkSw, bias, out);
}